// Round 9
// baseline (19073.859 us; speedup 1.0000x reference)
//
#include <hip/hip_runtime.h>

// BasicGRU persistent kernel for MI355X (gfx950) — round 9.
//
// R8 structure (proven: 14.6ms stable) with two surgical fixes:
//  1. COMPACT FLAGS: slots 4B apart -> the group's 64 flags live in 4 cache
//     lines; each poll iteration is ONE coalesced 256B gather instead of a
//     64-line fan-out (R8's 64B spacing made every poll iteration touch 64
//     distinct lines -> wide L3 fan-out on the critical path, twice/step).
//  2. SCRATCH DOUBLE-BUFFER by t-parity -> the pre-write WAR __syncthreads
//     in each phase is unnecessary (readers of a parity buffer finished >=2
//     barriers ago). 2 barriers/step instead of 4.
//
// Everything else identical to R8:
//  - 8 groups (g=blockIdx&7) x 32 wgs (rank=blockIdx>>3) x 8 batch rows.
//    Merged roles: per wg, phase1 = r-tile [16r,+16) + z-tile 512+[16r,+16)
//    (shared A-frags; zt + own-h stay in registers), phase2 = u-tile.
//  - exchange: h/hr packed u32 (bf16hi<<16|lo), parity double-buffered,
//    relaxed agent-scope loads/stores (sc0 sc1). Producer: data stores ->
//    s_waitcnt vmcnt(0) -> per-wave flag (monotonic 2t+1/2t+2). Consumer:
//    64-lane flag gather + __all, s_sleep(1) backoff.
//  - post-poll path: 16 batched coherent u64 loads -> unpack -> 24 MFMA ->
//    LDS reduce. x-only MFMAs and split_x(t+1) hidden before the polls.
//  - weights: hi bf16 in VGPRs (72/wave), lo bf16 in LDS (73.7KB);
//    3-product bf16-split MFMA. WAR on parity buffers: transitive flag chain.
//
// ws: h2 u32[2][64][512] @0 (256KB); hr2 @262144 (256KB);
//     flags @524288: 8 groups x 64 x u32 (2KB). total 526336, memset 0.

#define TT 2048
#define DD 256
#define UU 512

typedef short bf16x8 __attribute__((ext_vector_type(8)));
typedef float f32x4 __attribute__((ext_vector_type(4)));
typedef unsigned int u32;
typedef unsigned long long u64;

#define H2_OFF 0
#define HR2_OFF 262144
#define FLAG_OFF 524288
#define WS_BYTES 526336

__device__ inline unsigned short f2bf(float f) {
  unsigned u = __builtin_bit_cast(unsigned, f);
  u += 0x7FFFu + ((u >> 16) & 1u);  // round-nearest-even
  return (unsigned short)(u >> 16);
}
__device__ inline float bf2f(unsigned short b) {
  unsigned u = ((unsigned)b) << 16;
  return __builtin_bit_cast(float, u);
}
__device__ inline u32 ld_coh_u32(const u32* p) {
  return __hip_atomic_load(p, __ATOMIC_RELAXED, __HIP_MEMORY_SCOPE_AGENT);
}
__device__ inline u64 ld_coh_u64(const u64* p) {
  return __hip_atomic_load(p, __ATOMIC_RELAXED, __HIP_MEMORY_SCOPE_AGENT);
}
__device__ inline void st_coh_u32(u32* p, u32 v) {
  __hip_atomic_store(p, v, __ATOMIC_RELAXED, __HIP_MEMORY_SCOPE_AGENT);
}

#define MFMA(A, B, C) __builtin_amdgcn_mfma_f32_16x16x32_bf16((A), (B), (C), 0, 0, 0)

__global__ __launch_bounds__(256, 1) void gru_persist(
    const float* __restrict__ x, const float* __restrict__ Wk,
    const float* __restrict__ Wrk, const float* __restrict__ brk,
    const float* __restrict__ Wu, const float* __restrict__ Wur,
    const float* __restrict__ bur, float* __restrict__ out,
    unsigned char* __restrict__ ws) {
  __shared__ short wlo[36864];     // lo weights [3 tiles][24 ch][64 lane][8]
  __shared__ float scratch[6144];  // ph1: {r,z}@(t&1)*2048; ph2: u@4096+(t&1)*1024

  const int wgid = blockIdx.x;
  const int g = wgid & 7;          // group (8 batch rows [8g,8g+8))
  const int rank = wgid >> 3;      // 0..31 -> 16-col tile
  const int tid = threadIdx.x;
  const int lane = tid & 63;
  const int wv = tid >> 6;
  const int kgrp = lane >> 4;
  const int c = lane & 15;

  const int C1 = 16 * rank;        // r-gate / u cols
  const int C1z = 512 + C1;        // z-gate cols

  // ---- one-time: hi weight fragments -> VGPRs
  bf16x8 wrhi[6], wzhi[6], wuhi[6];
#pragma unroll
  for (int j = 0; j < 6; ++j) {
    const int kb = 32 * (wv + 4 * j) + kgrp * 8;
#pragma unroll
    for (int i = 0; i < 8; ++i) {
      const int k = kb + i;
      float vr = (k < DD) ? Wk[(size_t)k * 1024 + C1 + c]
                          : Wrk[(size_t)(k - DD) * 1024 + C1 + c];
      float vz = (k < DD) ? Wk[(size_t)k * 1024 + C1z + c]
                          : Wrk[(size_t)(k - DD) * 1024 + C1z + c];
      float vu = (k < DD) ? Wu[(size_t)k * UU + C1 + c]
                          : Wur[(size_t)(k - DD) * UU + C1 + c];
      wrhi[j][i] = (short)f2bf(vr);
      wzhi[j][i] = (short)f2bf(vz);
      wuhi[j][i] = (short)f2bf(vu);
    }
  }
  // ---- one-time: lo weights -> LDS (cooperative; T0=r, T1=z, T2=u)
  for (int idx = tid; idx < 3 * 12288; idx += 256) {
    const int T = idx / 12288;
    const int rem = idx - T * 12288;
    const int k = rem >> 4, cc = rem & 15;
    float v;
    if (T == 0)
      v = (k < DD) ? Wk[(size_t)k * 1024 + C1 + cc]
                   : Wrk[(size_t)(k - DD) * 1024 + C1 + cc];
    else if (T == 1)
      v = (k < DD) ? Wk[(size_t)k * 1024 + C1z + cc]
                   : Wrk[(size_t)(k - DD) * 1024 + C1z + cc];
    else
      v = (k < DD) ? Wu[(size_t)k * UU + C1 + cc]
                   : Wur[(size_t)(k - DD) * UU + C1 + cc];
    unsigned short hb = f2bf(v);
    const int ch = k >> 5, kk = k & 31;
    wlo[((T * 24 + ch) * 64 + (kk >> 3) * 16 + cc) * 8 + (kk & 7)] =
        (short)f2bf(v - bf2f(hb));
  }
  __syncthreads();

  u32* h2 = (u32*)(ws + H2_OFF);    // [2][64 rows][512]
  u32* hr2 = (u32*)(ws + HR2_OFF);  // [2][64 rows][512]
  u32* flg = (u32*)(ws + FLAG_OFF) + (size_t)g * 64;  // 64 x u32, 4B apart
  u32* myflag = flg + (rank * 2 + wv);                // used by wv<2 only

  const int bl = tid >> 4, cl = tid & 15;  // reduce coords (bl<8 meaningful)
  const float b_r = brk[C1 + cl];
  const float b_z = brk[C1z + cl];
  const float b_u = bur[C1 + cl];

  const int arow = c & 7;  // A rows 8..15 duplicate 0..7 (C rows 8..15 unused)
  const float* xrow = x + (size_t)(8 * g + arow) * TT * DD;

  bf16x8 xhi[2], xlo[2];
  auto split_x = [&](int t) {
#pragma unroll
    for (int j = 0; j < 2; ++j) {
      const float* p = xrow + (size_t)t * DD + 32 * wv + 128 * j + kgrp * 8;
      f32x4 v0 = *(const f32x4*)p;
      f32x4 v1 = *(const f32x4*)(p + 4);
#pragma unroll
      for (int i = 0; i < 4; ++i) {
        unsigned short hb = f2bf(v0[i]);
        xhi[j][i] = (short)hb;
        xlo[j][i] = (short)f2bf(v0[i] - bf2f(hb));
        unsigned short hb2 = f2bf(v1[i]);
        xhi[j][4 + i] = (short)hb2;
        xlo[j][4 + i] = (short)f2bf(v1[i] - bf2f(hb2));
      }
    }
  };

  auto poll = [&](u32 need) {  // one coalesced 256B gather per iteration
    const u32* p = flg + lane;
    while (!__all(ld_coh_u32(p) >= need)) __builtin_amdgcn_s_sleep(1);
  };

  auto chunk3 = [&](const bf16x8& ahi, const bf16x8& alo, const bf16x8& bhi,
                    const bf16x8& blo, f32x4& acc) {
    acc = MFMA(ahi, bhi, acc);
    acc = MFMA(ahi, blo, acc);
    acc = MFMA(alo, bhi, acc);
  };

  split_x(0);
  float hown = 0.f, zt_reg = 0.f;  // own h / update gate (threads tid<128)
  f32x4 ar = {0.f, 0.f, 0.f, 0.f}, az = ar;
#pragma unroll
  for (int j = 0; j < 2; ++j) {  // t=0 x-partials
    bf16x8 br = *(const bf16x8*)&wlo[((wv + 4 * j) * 64 + lane) * 8];
    bf16x8 bz = *(const bf16x8*)&wlo[((24 + wv + 4 * j) * 64 + lane) * 8];
    chunk3(xhi[j], xlo[j], wrhi[j], br, ar);
    chunk3(xhi[j], xlo[j], wzhi[j], bz, az);
  }

  for (int t = 0; t < TT; ++t) {
    const int s1 = (t & 1) * 2048;         // phase-1 scratch base (r, z+1024)
    const int s2 = 4096 + (t & 1) * 1024;  // phase-2 scratch base (u)

    // ================= phase 1: wait h(t-1); r+z h-part GEMM
    poll(2 * (u32)t);
    {
      const int bh = (t + 1) & 1;
      const u64* hb = (const u64*)(h2 + ((size_t)(bh * 64 + 8 * g + arow)) * 512 +
                                   32 * wv + kgrp * 8);
      u64 Q[16];
#pragma unroll
      for (int p = 0; p < 4; ++p) {
        Q[4 * p + 0] = ld_coh_u64(hb + 64 * p + 0);
        Q[4 * p + 1] = ld_coh_u64(hb + 64 * p + 1);
        Q[4 * p + 2] = ld_coh_u64(hb + 64 * p + 2);
        Q[4 * p + 3] = ld_coh_u64(hb + 64 * p + 3);
      }
#pragma unroll
      for (int p = 0; p < 4; ++p) {
        bf16x8 ahi, alo;
#pragma unroll
        for (int i = 0; i < 4; ++i) {
          u32 lo32 = (u32)Q[4 * p + i], hi32 = (u32)(Q[4 * p + i] >> 32);
          ahi[2 * i] = (short)(lo32 >> 16);
          alo[2 * i] = (short)lo32;
          ahi[2 * i + 1] = (short)(hi32 >> 16);
          alo[2 * i + 1] = (short)hi32;
        }
        const int j = p + 2;
        bf16x8 br = *(const bf16x8*)&wlo[((wv + 4 * j) * 64 + lane) * 8];
        bf16x8 bz = *(const bf16x8*)&wlo[((24 + wv + 4 * j) * 64 + lane) * 8];
        chunk3(ahi, alo, wrhi[j], br, ar);
        chunk3(ahi, alo, wzhi[j], bz, az);
      }
    }
#pragma unroll
    for (int r = 0; r < 4; ++r) {
      scratch[s1 + wv * 256 + (kgrp * 4 + r) * 16 + c] = ar[r];
      scratch[s1 + 1024 + wv * 256 + (kgrp * 4 + r) * 16 + c] = az[r];
    }
    __syncthreads();
    if (tid < 128) {
      float rv = (scratch[s1 + tid] + scratch[s1 + 256 + tid]) +
                 (scratch[s1 + 512 + tid] + scratch[s1 + 768 + tid]) + b_r;
      float zv = (scratch[s1 + 1024 + tid] + scratch[s1 + 1280 + tid]) +
                 (scratch[s1 + 1536 + tid] + scratch[s1 + 1792 + tid]) + b_z;
      float rg = 1.f / (1.f + __expf(-rv));
      zt_reg = 1.f / (1.f + __expf(-zv));
      float hrv = hown * rg;
      unsigned short hb = f2bf(hrv);
      unsigned short lb = f2bf(hrv - bf2f(hb));
      st_coh_u32(hr2 + ((size_t)((t & 1) * 64 + 8 * g + bl)) * 512 + C1 + cl,
                 ((u32)hb << 16) | lb);
    }
    asm volatile("s_waitcnt vmcnt(0)" ::: "memory");
    if (wv < 2 && lane == 0) st_coh_u32(myflag, 2 * (u32)t + 1);

    // ================= phase 2: xu pre-GEMM + x(t+1) split (hidden), then hr
    f32x4 au = {0.f, 0.f, 0.f, 0.f};
#pragma unroll
    for (int j = 0; j < 2; ++j) {
      bf16x8 bu = *(const bf16x8*)&wlo[((48 + wv + 4 * j) * 64 + lane) * 8];
      chunk3(xhi[j], xlo[j], wuhi[j], bu, au);
    }
    if (t + 1 < TT) split_x(t + 1);
    poll(2 * (u32)t + 1);
    {
      const u64* hrb = (const u64*)(hr2 + ((size_t)((t & 1) * 64 + 8 * g + arow)) * 512 +
                                    32 * wv + kgrp * 8);
      u64 Q[16];
#pragma unroll
      for (int p = 0; p < 4; ++p) {
        Q[4 * p + 0] = ld_coh_u64(hrb + 64 * p + 0);
        Q[4 * p + 1] = ld_coh_u64(hrb + 64 * p + 1);
        Q[4 * p + 2] = ld_coh_u64(hrb + 64 * p + 2);
        Q[4 * p + 3] = ld_coh_u64(hrb + 64 * p + 3);
      }
#pragma unroll
      for (int p = 0; p < 4; ++p) {
        bf16x8 ahi, alo;
#pragma unroll
        for (int i = 0; i < 4; ++i) {
          u32 lo32 = (u32)Q[4 * p + i], hi32 = (u32)(Q[4 * p + i] >> 32);
          ahi[2 * i] = (short)(lo32 >> 16);
          alo[2 * i] = (short)lo32;
          ahi[2 * i + 1] = (short)(hi32 >> 16);
          alo[2 * i + 1] = (short)hi32;
        }
        const int j = p + 2;
        bf16x8 bu = *(const bf16x8*)&wlo[((48 + wv + 4 * j) * 64 + lane) * 8];
        chunk3(ahi, alo, wuhi[j], bu, au);
      }
    }
#pragma unroll
    for (int r = 0; r < 4; ++r)
      scratch[s2 + wv * 256 + (kgrp * 4 + r) * 16 + c] = au[r];
    __syncthreads();
    if (tid < 128) {
      float uv = (scratch[s2 + tid] + scratch[s2 + 256 + tid]) +
                 (scratch[s2 + 512 + tid] + scratch[s2 + 768 + tid]) + b_u;
      float e = __expf(2.f * uv);
      float th = 1.f - 2.f / (e + 1.f);  // tanh(uv)
      float hn = hown + zt_reg * (th - hown);
      hown = hn;
      unsigned short hb = f2bf(hn);
      unsigned short lb = f2bf(hn - bf2f(hb));
      st_coh_u32(h2 + ((size_t)((t & 1) * 64 + 8 * g + bl)) * 512 + C1 + cl,
                 ((u32)hb << 16) | lb);
      if (t == TT - 1) out[(size_t)(8 * g + bl) * UU + C1 + cl] = hn;
    }
    asm volatile("s_waitcnt vmcnt(0)" ::: "memory");
    if (wv < 2 && lane == 0) st_coh_u32(myflag, 2 * (u32)t + 2);

    // ---- next-step phase-1 x-partials (hidden before next poll)
    ar = (f32x4){0.f, 0.f, 0.f, 0.f};
    az = (f32x4){0.f, 0.f, 0.f, 0.f};
    if (t + 1 < TT) {
#pragma unroll
      for (int j = 0; j < 2; ++j) {
        bf16x8 br = *(const bf16x8*)&wlo[((wv + 4 * j) * 64 + lane) * 8];
        bf16x8 bz = *(const bf16x8*)&wlo[((24 + wv + 4 * j) * 64 + lane) * 8];
        chunk3(xhi[j], xlo[j], wrhi[j], br, ar);
        chunk3(xhi[j], xlo[j], wzhi[j], bz, az);
      }
    }
  }
}

extern "C" void kernel_launch(void* const* d_in, const int* in_sizes, int n_in,
                              void* d_out, int out_size, void* d_ws,
                              size_t ws_size, hipStream_t stream) {
  (void)in_sizes; (void)n_in; (void)out_size; (void)ws_size;
  hipMemsetAsync(d_ws, 0, WS_BYTES, stream);  // h(-1)=0, flags=0 (ready @ t=0)
  gru_persist<<<dim3(256), dim3(256), 0, stream>>>(
      (const float*)d_in[0], (const float*)d_in[1], (const float*)d_in[2],
      (const float*)d_in[3], (const float*)d_in[4], (const float*)d_in[5],
      (const float*)d_in[6], (float*)d_out, (unsigned char*)d_ws);
}

// Round 10
// 15344.092 us; speedup vs baseline: 1.2431x; 1.2431x over previous
//
#include <hip/hip_runtime.h>

// BasicGRU persistent kernel for MI355X (gfx950) — round 10.
//
// R8 skeleton (proven 14.6ms) + R9's scratch double-buffer (2 barriers/step)
// + two latency-shadow moves. R9's regression was the COMPACT FLAG LINES:
// 16 producer wgs stored to the same 64B line -> serialized exclusive-
// ownership convoy. Flags are back to R8's 64B-per-writer spacing (reads are
// a single 64-lane gather either way; writer-line privacy is what matters).
//
// Shadow moves (fill the exposed post-poll data-load RTs with x-only work):
//  - phase 1: poll h -> ISSUE 16 h loads -> xu x-partial GEMM (au) -> consume
//    h chunks (r/z MFMAs). (R8 ran xu before poll2 where it hid nothing in
//    steady state: spins are ~0 when all wgs are symmetric.)
//  - phase 2: poll hr -> ISSUE 16 hr loads -> ar/az x-partials for t+1
//    (split_x(t+1) completes before poll2) -> consume hr chunks (u MFMAs).
//
// Everything else identical to R8:
//  - 8 groups (g=blockIdx&7) x 32 wgs (rank) x 8 batch rows; merged roles
//    (r-tile + z-tile phase 1, u-tile phase 2); zt + own-h in registers.
//  - h/hr packed u32 (bf16hi<<16|lo), parity double-buffered, relaxed
//    agent-scope loads/stores. Producer: stores -> vmcnt(0) -> per-wave flag
//    (2t+1 / 2t+2, 64B apart). Consumer: 64-lane gather + __all + s_sleep.
//  - weights: hi bf16 in VGPRs (72/wave), lo bf16 in LDS; 3-product
//    bf16-split MFMA. WAR on parity buffers: transitive flag chain.
//
// ws: h2 u32[2][64][512] @0 (256KB); hr2 @262144 (256KB);
//     flags @524288: 8 groups x 64 slots x 64B (32KB). total 557056, memset 0.

#define TT 2048
#define DD 256
#define UU 512

typedef short bf16x8 __attribute__((ext_vector_type(8)));
typedef float f32x4 __attribute__((ext_vector_type(4)));
typedef unsigned int u32;
typedef unsigned long long u64;

#define H2_OFF 0
#define HR2_OFF 262144
#define FLAG_OFF 524288
#define WS_BYTES 557056

__device__ inline unsigned short f2bf(float f) {
  unsigned u = __builtin_bit_cast(unsigned, f);
  u += 0x7FFFu + ((u >> 16) & 1u);  // round-nearest-even
  return (unsigned short)(u >> 16);
}
__device__ inline float bf2f(unsigned short b) {
  unsigned u = ((unsigned)b) << 16;
  return __builtin_bit_cast(float, u);
}
__device__ inline u32 ld_coh_u32(const u32* p) {
  return __hip_atomic_load(p, __ATOMIC_RELAXED, __HIP_MEMORY_SCOPE_AGENT);
}
__device__ inline u64 ld_coh_u64(const u64* p) {
  return __hip_atomic_load(p, __ATOMIC_RELAXED, __HIP_MEMORY_SCOPE_AGENT);
}
__device__ inline void st_coh_u32(u32* p, u32 v) {
  __hip_atomic_store(p, v, __ATOMIC_RELAXED, __HIP_MEMORY_SCOPE_AGENT);
}

#define MFMA(A, B, C) __builtin_amdgcn_mfma_f32_16x16x32_bf16((A), (B), (C), 0, 0, 0)

__global__ __launch_bounds__(256, 1) void gru_persist(
    const float* __restrict__ x, const float* __restrict__ Wk,
    const float* __restrict__ Wrk, const float* __restrict__ brk,
    const float* __restrict__ Wu, const float* __restrict__ Wur,
    const float* __restrict__ bur, float* __restrict__ out,
    unsigned char* __restrict__ ws) {
  __shared__ short wlo[36864];     // lo weights [3 tiles][24 ch][64 lane][8]
  __shared__ float scratch[6144];  // ph1 {r,z}@(t&1)*2048; ph2 u@4096+(t&1)*1024

  const int wgid = blockIdx.x;
  const int g = wgid & 7;          // group (8 batch rows [8g,8g+8))
  const int rank = wgid >> 3;      // 0..31 -> 16-col tile
  const int tid = threadIdx.x;
  const int lane = tid & 63;
  const int wv = tid >> 6;
  const int kgrp = lane >> 4;
  const int c = lane & 15;

  const int C1 = 16 * rank;        // r-gate / u cols
  const int C1z = 512 + C1;        // z-gate cols

  // ---- one-time: hi weight fragments -> VGPRs
  bf16x8 wrhi[6], wzhi[6], wuhi[6];
#pragma unroll
  for (int j = 0; j < 6; ++j) {
    const int kb = 32 * (wv + 4 * j) + kgrp * 8;
#pragma unroll
    for (int i = 0; i < 8; ++i) {
      const int k = kb + i;
      float vr = (k < DD) ? Wk[(size_t)k * 1024 + C1 + c]
                          : Wrk[(size_t)(k - DD) * 1024 + C1 + c];
      float vz = (k < DD) ? Wk[(size_t)k * 1024 + C1z + c]
                          : Wrk[(size_t)(k - DD) * 1024 + C1z + c];
      float vu = (k < DD) ? Wu[(size_t)k * UU + C1 + c]
                          : Wur[(size_t)(k - DD) * UU + C1 + c];
      wrhi[j][i] = (short)f2bf(vr);
      wzhi[j][i] = (short)f2bf(vz);
      wuhi[j][i] = (short)f2bf(vu);
    }
  }
  // ---- one-time: lo weights -> LDS (cooperative; T0=r, T1=z, T2=u)
  for (int idx = tid; idx < 3 * 12288; idx += 256) {
    const int T = idx / 12288;
    const int rem = idx - T * 12288;
    const int k = rem >> 4, cc = rem & 15;
    float v;
    if (T == 0)
      v = (k < DD) ? Wk[(size_t)k * 1024 + C1 + cc]
                   : Wrk[(size_t)(k - DD) * 1024 + C1 + cc];
    else if (T == 1)
      v = (k < DD) ? Wk[(size_t)k * 1024 + C1z + cc]
                   : Wrk[(size_t)(k - DD) * 1024 + C1z + cc];
    else
      v = (k < DD) ? Wu[(size_t)k * UU + C1 + cc]
                   : Wur[(size_t)(k - DD) * UU + C1 + cc];
    unsigned short hb = f2bf(v);
    const int ch = k >> 5, kk = k & 31;
    wlo[((T * 24 + ch) * 64 + (kk >> 3) * 16 + cc) * 8 + (kk & 7)] =
        (short)f2bf(v - bf2f(hb));
  }
  __syncthreads();

  u32* h2 = (u32*)(ws + H2_OFF);    // [2][64 rows][512]
  u32* hr2 = (u32*)(ws + HR2_OFF);  // [2][64 rows][512]
  u32* flg = (u32*)(ws + FLAG_OFF) + (size_t)g * 1024;  // 64 slots x 64B
  u32* myflag = flg + (rank * 2 + wv) * 16;             // used by wv<2 only

  const int bl = tid >> 4, cl = tid & 15;  // reduce coords (bl<8 meaningful)
  const float b_r = brk[C1 + cl];
  const float b_z = brk[C1z + cl];
  const float b_u = bur[C1 + cl];

  const int arow = c & 7;  // A rows 8..15 duplicate 0..7 (C rows 8..15 unused)
  const float* xrow = x + (size_t)(8 * g + arow) * TT * DD;

  bf16x8 xhi[2], xlo[2];
  auto split_x = [&](int t) {
#pragma unroll
    for (int j = 0; j < 2; ++j) {
      const float* p = xrow + (size_t)t * DD + 32 * wv + 128 * j + kgrp * 8;
      f32x4 v0 = *(const f32x4*)p;
      f32x4 v1 = *(const f32x4*)(p + 4);
#pragma unroll
      for (int i = 0; i < 4; ++i) {
        unsigned short hb = f2bf(v0[i]);
        xhi[j][i] = (short)hb;
        xlo[j][i] = (short)f2bf(v0[i] - bf2f(hb));
        unsigned short hb2 = f2bf(v1[i]);
        xhi[j][4 + i] = (short)hb2;
        xlo[j][4 + i] = (short)f2bf(v1[i] - bf2f(hb2));
      }
    }
  };

  auto poll = [&](u32 need) {  // one 64-lane gather per iteration
    const u32* p = flg + lane * 16;
    while (!__all(ld_coh_u32(p) >= need)) __builtin_amdgcn_s_sleep(1);
  };

  auto chunk3 = [&](const bf16x8& ahi, const bf16x8& alo, const bf16x8& bhi,
                    const bf16x8& blo, f32x4& acc) {
    acc = MFMA(ahi, bhi, acc);
    acc = MFMA(ahi, blo, acc);
    acc = MFMA(alo, bhi, acc);
  };

  split_x(0);
  float hown = 0.f, zt_reg = 0.f;  // own h / update gate (threads tid<128)
  f32x4 ar = {0.f, 0.f, 0.f, 0.f}, az = ar;
#pragma unroll
  for (int j = 0; j < 2; ++j) {  // t=0 phase-1 x-partials
    bf16x8 br = *(const bf16x8*)&wlo[((wv + 4 * j) * 64 + lane) * 8];
    bf16x8 bz = *(const bf16x8*)&wlo[((24 + wv + 4 * j) * 64 + lane) * 8];
    chunk3(xhi[j], xlo[j], wrhi[j], br, ar);
    chunk3(xhi[j], xlo[j], wzhi[j], bz, az);
  }

  for (int t = 0; t < TT; ++t) {
    const int s1 = (t & 1) * 2048;         // phase-1 scratch base (r, z+1024)
    const int s2 = 4096 + (t & 1) * 1024;  // phase-2 scratch base (u)

    // ================= phase 1: wait h(t-1); issue h loads; xu in shadow
    poll(2 * (u32)t);
    f32x4 au = {0.f, 0.f, 0.f, 0.f};
    {
      const int bh = (t + 1) & 1;
      const u64* hb = (const u64*)(h2 + ((size_t)(bh * 64 + 8 * g + arow)) * 512 +
                                   32 * wv + kgrp * 8);
      u64 Q[16];
#pragma unroll
      for (int p = 0; p < 4; ++p) {
        Q[4 * p + 0] = ld_coh_u64(hb + 64 * p + 0);
        Q[4 * p + 1] = ld_coh_u64(hb + 64 * p + 1);
        Q[4 * p + 2] = ld_coh_u64(hb + 64 * p + 2);
        Q[4 * p + 3] = ld_coh_u64(hb + 64 * p + 3);
      }
      // ---- shadow: xu x-partial GEMM (no dependence on Q)
#pragma unroll
      for (int j = 0; j < 2; ++j) {
        bf16x8 bu = *(const bf16x8*)&wlo[((48 + wv + 4 * j) * 64 + lane) * 8];
        chunk3(xhi[j], xlo[j], wuhi[j], bu, au);
      }
      // ---- consume h chunks: r/z MFMAs
#pragma unroll
      for (int p = 0; p < 4; ++p) {
        bf16x8 ahi, alo;
#pragma unroll
        for (int i = 0; i < 4; ++i) {
          u32 lo32 = (u32)Q[4 * p + i], hi32 = (u32)(Q[4 * p + i] >> 32);
          ahi[2 * i] = (short)(lo32 >> 16);
          alo[2 * i] = (short)lo32;
          ahi[2 * i + 1] = (short)(hi32 >> 16);
          alo[2 * i + 1] = (short)hi32;
        }
        const int j = p + 2;
        bf16x8 br = *(const bf16x8*)&wlo[((wv + 4 * j) * 64 + lane) * 8];
        bf16x8 bz = *(const bf16x8*)&wlo[((24 + wv + 4 * j) * 64 + lane) * 8];
        chunk3(ahi, alo, wrhi[j], br, ar);
        chunk3(ahi, alo, wzhi[j], bz, az);
      }
    }
#pragma unroll
    for (int r = 0; r < 4; ++r) {
      scratch[s1 + wv * 256 + (kgrp * 4 + r) * 16 + c] = ar[r];
      scratch[s1 + 1024 + wv * 256 + (kgrp * 4 + r) * 16 + c] = az[r];
    }
    __syncthreads();
    if (tid < 128) {
      float rv = (scratch[s1 + tid] + scratch[s1 + 256 + tid]) +
                 (scratch[s1 + 512 + tid] + scratch[s1 + 768 + tid]) + b_r;
      float zv = (scratch[s1 + 1024 + tid] + scratch[s1 + 1280 + tid]) +
                 (scratch[s1 + 1536 + tid] + scratch[s1 + 1792 + tid]) + b_z;
      float rg = 1.f / (1.f + __expf(-rv));
      zt_reg = 1.f / (1.f + __expf(-zv));
      float hrv = hown * rg;
      unsigned short hb = f2bf(hrv);
      unsigned short lb = f2bf(hrv - bf2f(hb));
      st_coh_u32(hr2 + ((size_t)((t & 1) * 64 + 8 * g + bl)) * 512 + C1 + cl,
                 ((u32)hb << 16) | lb);
    }
    asm volatile("s_waitcnt vmcnt(0)" ::: "memory");
    if (wv < 2 && lane == 0) st_coh_u32(myflag, 2 * (u32)t + 1);

    // ================= phase 2: x(t+1) split; wait hr; ar/az in shadow
    if (t + 1 < TT) split_x(t + 1);
    poll(2 * (u32)t + 1);
    ar = (f32x4){0.f, 0.f, 0.f, 0.f};
    az = (f32x4){0.f, 0.f, 0.f, 0.f};
    {
      const u64* hrb = (const u64*)(hr2 + ((size_t)((t & 1) * 64 + 8 * g + arow)) * 512 +
                                    32 * wv + kgrp * 8);
      u64 Q[16];
#pragma unroll
      for (int p = 0; p < 4; ++p) {
        Q[4 * p + 0] = ld_coh_u64(hrb + 64 * p + 0);
        Q[4 * p + 1] = ld_coh_u64(hrb + 64 * p + 1);
        Q[4 * p + 2] = ld_coh_u64(hrb + 64 * p + 2);
        Q[4 * p + 3] = ld_coh_u64(hrb + 64 * p + 3);
      }
      // ---- shadow: next-step phase-1 x-partials (uses x(t+1) fragments)
      if (t + 1 < TT) {
#pragma unroll
        for (int j = 0; j < 2; ++j) {
          bf16x8 br = *(const bf16x8*)&wlo[((wv + 4 * j) * 64 + lane) * 8];
          bf16x8 bz = *(const bf16x8*)&wlo[((24 + wv + 4 * j) * 64 + lane) * 8];
          chunk3(xhi[j], xlo[j], wrhi[j], br, ar);
          chunk3(xhi[j], xlo[j], wzhi[j], bz, az);
        }
      }
      // ---- consume hr chunks: u MFMAs
#pragma unroll
      for (int p = 0; p < 4; ++p) {
        bf16x8 ahi, alo;
#pragma unroll
        for (int i = 0; i < 4; ++i) {
          u32 lo32 = (u32)Q[4 * p + i], hi32 = (u32)(Q[4 * p + i] >> 32);
          ahi[2 * i] = (short)(lo32 >> 16);
          alo[2 * i] = (short)lo32;
          ahi[2 * i + 1] = (short)(hi32 >> 16);
          alo[2 * i + 1] = (short)hi32;
        }
        const int j = p + 2;
        bf16x8 bu = *(const bf16x8*)&wlo[((48 + wv + 4 * j) * 64 + lane) * 8];
        chunk3(ahi, alo, wuhi[j], bu, au);
      }
    }
#pragma unroll
    for (int r = 0; r < 4; ++r)
      scratch[s2 + wv * 256 + (kgrp * 4 + r) * 16 + c] = au[r];
    __syncthreads();
    if (tid < 128) {
      float uv = (scratch[s2 + tid] + scratch[s2 + 256 + tid]) +
                 (scratch[s2 + 512 + tid] + scratch[s2 + 768 + tid]) + b_u;
      float e = __expf(2.f * uv);
      float th = 1.f - 2.f / (e + 1.f);  // tanh(uv)
      float hn = hown + zt_reg * (th - hown);
      hown = hn;
      unsigned short hb = f2bf(hn);
      unsigned short lb = f2bf(hn - bf2f(hb));
      st_coh_u32(h2 + ((size_t)((t & 1) * 64 + 8 * g + bl)) * 512 + C1 + cl,
                 ((u32)hb << 16) | lb);
      if (t == TT - 1) out[(size_t)(8 * g + bl) * UU + C1 + cl] = hn;
    }
    asm volatile("s_waitcnt vmcnt(0)" ::: "memory");
    if (wv < 2 && lane == 0) st_coh_u32(myflag, 2 * (u32)t + 2);
  }
}

extern "C" void kernel_launch(void* const* d_in, const int* in_sizes, int n_in,
                              void* d_out, int out_size, void* d_ws,
                              size_t ws_size, hipStream_t stream) {
  (void)in_sizes; (void)n_in; (void)out_size; (void)ws_size;
  hipMemsetAsync(d_ws, 0, WS_BYTES, stream);  // h(-1)=0, flags=0 (ready @ t=0)
  gru_persist<<<dim3(256), dim3(256), 0, stream>>>(
      (const float*)d_in[0], (const float*)d_in[1], (const float*)d_in[2],
      (const float*)d_in[3], (const float*)d_in[4], (const float*)d_in[5],
      (const float*)d_in[6], (float*)d_out, (unsigned char*)d_ws);
}

// Round 12
// 15253.830 us; speedup vs baseline: 1.2504x; 1.0059x over previous
//
#include <hip/hip_runtime.h>

// BasicGRU persistent kernel for MI355X (gfx950) — round 12.
//
// EXACT R8 skeleton (proven 14.6ms; R9/R10/R11 variants all regressed or
// hung and are reverted) with ONE change:
//
//  FINE-GRAINED PER-WAVE DEPENDENCY POLLING. R8 polled all 64 flag slots ->
//  every wave waited on the globally slowest wg and each poll touched 64
//  cache lines. But wave wv consumes only h/hr K-chunks m in {wv, wv+4,
//  wv+8, wv+12}, produced by ranks {2m, 2m+1} = 8 wgs -> 16 flag slots.
//  Each wave polls exactly those (4 lanes per slot, coalesced; 16 lines per
//  gather): starts when ITS producers are done (dodges 3/4 of stragglers)
//  and cuts poll-read traffic 4x.
//
//  WAR safety unchanged: the wg's 4-wave dep union covers all 32 ranks every
//  step, so the transitive flag chain still guarantees all readers of
//  h(t-1) retired before h(t+1) overwrites the parity slot (flag 2t+3 from
//  all ranks => every wg passed phase-1 of t+1 => all h(t-1) loads retired).
//
// Structure (R8): 8 groups (g=blockIdx&7) x 32 wgs (rank) x 8 batch rows;
//  merged roles: phase1 = r-tile [16r,+16) + z-tile 512+[16r,+16) (shared
//  A-frags; zt + own-h in registers), phase2 = u-tile [16r,+16).
//  h/hr packed u32 (bf16hi<<16|lo), parity double-buffered, relaxed
//  agent-scope (sc0 sc1) loads/stores. Producer: data stores -> vmcnt(0) ->
//  per-wave flag (2t+1 / 2t+2, 64B apart, waves 0,1). Batched 16 u64
//  coherent chunk loads; weights hi bf16 in VGPRs + lo bf16 in LDS;
//  3-product bf16-split MFMA (~1.5e-5 rel).
//
// ws: h2 u32[2][64][512] @0 (256KB); hr2 @262144 (256KB);
//     flags @524288: 8 groups x 64 slots x 64B (32KB). total 557056, memset 0.

#define TT 2048
#define DD 256
#define UU 512

typedef short bf16x8 __attribute__((ext_vector_type(8)));
typedef float f32x4 __attribute__((ext_vector_type(4)));
typedef unsigned int u32;
typedef unsigned long long u64;

#define H2_OFF 0
#define HR2_OFF 262144
#define FLAG_OFF 524288
#define WS_BYTES 557056

__device__ inline unsigned short f2bf(float f) {
  unsigned u = __builtin_bit_cast(unsigned, f);
  u += 0x7FFFu + ((u >> 16) & 1u);  // round-nearest-even
  return (unsigned short)(u >> 16);
}
__device__ inline float bf2f(unsigned short b) {
  unsigned u = ((unsigned)b) << 16;
  return __builtin_bit_cast(float, u);
}
__device__ inline u32 ld_coh_u32(const u32* p) {
  return __hip_atomic_load(p, __ATOMIC_RELAXED, __HIP_MEMORY_SCOPE_AGENT);
}
__device__ inline u64 ld_coh_u64(const u64* p) {
  return __hip_atomic_load(p, __ATOMIC_RELAXED, __HIP_MEMORY_SCOPE_AGENT);
}
__device__ inline void st_coh_u32(u32* p, u32 v) {
  __hip_atomic_store(p, v, __ATOMIC_RELAXED, __HIP_MEMORY_SCOPE_AGENT);
}

#define MFMA(A, B, C) __builtin_amdgcn_mfma_f32_16x16x32_bf16((A), (B), (C), 0, 0, 0)

__global__ __launch_bounds__(256, 1) void gru_persist(
    const float* __restrict__ x, const float* __restrict__ Wk,
    const float* __restrict__ Wrk, const float* __restrict__ brk,
    const float* __restrict__ Wu, const float* __restrict__ Wur,
    const float* __restrict__ bur, float* __restrict__ out,
    unsigned char* __restrict__ ws) {
  __shared__ short wlo[36864];    // lo weights [3 tiles][24 ch][64 lane][8]
  __shared__ float scratch[2304]; // ph1: r@0 z@1024; ph2: u@0 (+pad -> 83KB)

  const int wgid = blockIdx.x;
  const int g = wgid & 7;         // group (8 batch rows [8g,8g+8))
  const int rank = wgid >> 3;     // 0..31 -> 16-col tile
  const int tid = threadIdx.x;
  const int lane = tid & 63;
  const int wv = tid >> 6;
  const int kgrp = lane >> 4;
  const int c = lane & 15;

  const int C1 = 16 * rank;       // r-gate / u cols
  const int C1z = 512 + C1;       // z-gate cols

  // ---- one-time: hi weight fragments -> VGPRs
  bf16x8 wrhi[6], wzhi[6], wuhi[6];
#pragma unroll
  for (int j = 0; j < 6; ++j) {
    const int kb = 32 * (wv + 4 * j) + kgrp * 8;
#pragma unroll
    for (int i = 0; i < 8; ++i) {
      const int k = kb + i;
      float vr = (k < DD) ? Wk[(size_t)k * 1024 + C1 + c]
                          : Wrk[(size_t)(k - DD) * 1024 + C1 + c];
      float vz = (k < DD) ? Wk[(size_t)k * 1024 + C1z + c]
                          : Wrk[(size_t)(k - DD) * 1024 + C1z + c];
      float vu = (k < DD) ? Wu[(size_t)k * UU + C1 + c]
                          : Wur[(size_t)(k - DD) * UU + C1 + c];
      wrhi[j][i] = (short)f2bf(vr);
      wzhi[j][i] = (short)f2bf(vz);
      wuhi[j][i] = (short)f2bf(vu);
    }
  }
  // ---- one-time: lo weights -> LDS (cooperative; T0=r, T1=z, T2=u)
  for (int idx = tid; idx < 3 * 12288; idx += 256) {
    const int T = idx / 12288;
    const int rem = idx - T * 12288;
    const int k = rem >> 4, cc = rem & 15;
    float v;
    if (T == 0)
      v = (k < DD) ? Wk[(size_t)k * 1024 + C1 + cc]
                   : Wrk[(size_t)(k - DD) * 1024 + C1 + cc];
    else if (T == 1)
      v = (k < DD) ? Wk[(size_t)k * 1024 + C1z + cc]
                   : Wrk[(size_t)(k - DD) * 1024 + C1z + cc];
    else
      v = (k < DD) ? Wu[(size_t)k * UU + C1 + cc]
                   : Wur[(size_t)(k - DD) * UU + C1 + cc];
    unsigned short hb = f2bf(v);
    const int ch = k >> 5, kk = k & 31;
    wlo[((T * 24 + ch) * 64 + (kk >> 3) * 16 + cc) * 8 + (kk & 7)] =
        (short)f2bf(v - bf2f(hb));
  }
  __syncthreads();

  u32* h2 = (u32*)(ws + H2_OFF);    // [2][64 rows][512]
  u32* hr2 = (u32*)(ws + HR2_OFF);  // [2][64 rows][512]
  u32* flg = (u32*)(ws + FLAG_OFF) + (size_t)g * 1024;  // 64 slots x 64B
  u32* myflag = flg + (rank * 2 + wv) * 16;             // used by wv<2 only

  // ---- fine-grained dependency flag set for this wave (16 slots, 4 ln/slot)
  // wave wv consumes chunks m in {wv,wv+4,wv+8,wv+12} -> ranks 2m,2m+1,
  // each with 2 wave-flags.
  const int didx = lane & 15;
  const int dm = wv + 4 * (didx >> 2);
  const int drank = 2 * dm + ((didx >> 1) & 1);
  const u32* depflag = flg + (drank * 2 + (didx & 1)) * 16;

  const int bl = tid >> 4, cl = tid & 15;  // reduce coords (bl<8 meaningful)
  const float b_r = brk[C1 + cl];
  const float b_z = brk[C1z + cl];
  const float b_u = bur[C1 + cl];

  const int arow = c & 7;  // A rows 8..15 duplicate 0..7 (C rows 8..15 unused)
  const float* xrow = x + (size_t)(8 * g + arow) * TT * DD;

  bf16x8 xhi[2], xlo[2];
  auto split_x = [&](int t) {
#pragma unroll
    for (int j = 0; j < 2; ++j) {
      const float* p = xrow + (size_t)t * DD + 32 * wv + 128 * j + kgrp * 8;
      f32x4 v0 = *(const f32x4*)p;
      f32x4 v1 = *(const f32x4*)(p + 4);
#pragma unroll
      for (int i = 0; i < 4; ++i) {
        unsigned short hb = f2bf(v0[i]);
        xhi[j][i] = (short)hb;
        xlo[j][i] = (short)f2bf(v0[i] - bf2f(hb));
        unsigned short hb2 = f2bf(v1[i]);
        xhi[j][4 + i] = (short)hb2;
        xlo[j][4 + i] = (short)f2bf(v1[i] - bf2f(hb2));
      }
    }
  };

  auto poll = [&](u32 need) {  // 16-line gather over this wave's deps only
    while (!__all(ld_coh_u32(depflag) >= need)) __builtin_amdgcn_s_sleep(1);
  };

  auto chunk3 = [&](const bf16x8& ahi, const bf16x8& alo, const bf16x8& bhi,
                    const bf16x8& blo, f32x4& acc) {
    acc = MFMA(ahi, bhi, acc);
    acc = MFMA(ahi, blo, acc);
    acc = MFMA(alo, bhi, acc);
  };

  split_x(0);
  float hown = 0.f, zt_reg = 0.f;  // own h / update gate (threads tid<128)
  f32x4 ar = {0.f, 0.f, 0.f, 0.f}, az = ar;
#pragma unroll
  for (int j = 0; j < 2; ++j) {  // t=0 x-partials
    bf16x8 br = *(const bf16x8*)&wlo[((wv + 4 * j) * 64 + lane) * 8];
    bf16x8 bz = *(const bf16x8*)&wlo[((24 + wv + 4 * j) * 64 + lane) * 8];
    chunk3(xhi[j], xlo[j], wrhi[j], br, ar);
    chunk3(xhi[j], xlo[j], wzhi[j], bz, az);
  }

  for (int t = 0; t < TT; ++t) {
    // ================= phase 1: wait h(t-1) deps; r+z h-part GEMM
    poll(2 * (u32)t);
    {
      const int bh = (t + 1) & 1;
      const u64* hb = (const u64*)(h2 + ((size_t)(bh * 64 + 8 * g + arow)) * 512 +
                                   32 * wv + kgrp * 8);
      u64 Q[16];
#pragma unroll
      for (int p = 0; p < 4; ++p) {
        Q[4 * p + 0] = ld_coh_u64(hb + 64 * p + 0);
        Q[4 * p + 1] = ld_coh_u64(hb + 64 * p + 1);
        Q[4 * p + 2] = ld_coh_u64(hb + 64 * p + 2);
        Q[4 * p + 3] = ld_coh_u64(hb + 64 * p + 3);
      }
#pragma unroll
      for (int p = 0; p < 4; ++p) {
        bf16x8 ahi, alo;
#pragma unroll
        for (int i = 0; i < 4; ++i) {
          u32 lo32 = (u32)Q[4 * p + i], hi32 = (u32)(Q[4 * p + i] >> 32);
          ahi[2 * i] = (short)(lo32 >> 16);
          alo[2 * i] = (short)lo32;
          ahi[2 * i + 1] = (short)(hi32 >> 16);
          alo[2 * i + 1] = (short)hi32;
        }
        const int j = p + 2;
        bf16x8 br = *(const bf16x8*)&wlo[((wv + 4 * j) * 64 + lane) * 8];
        bf16x8 bz = *(const bf16x8*)&wlo[((24 + wv + 4 * j) * 64 + lane) * 8];
        chunk3(ahi, alo, wrhi[j], br, ar);
        chunk3(ahi, alo, wzhi[j], bz, az);
      }
    }
    __syncthreads();  // WAR: prev phase-2 reduce reads done
#pragma unroll
    for (int r = 0; r < 4; ++r) {
      scratch[wv * 256 + (kgrp * 4 + r) * 16 + c] = ar[r];
      scratch[1024 + wv * 256 + (kgrp * 4 + r) * 16 + c] = az[r];
    }
    __syncthreads();
    if (tid < 128) {
      float rv = (scratch[tid] + scratch[256 + tid]) +
                 (scratch[512 + tid] + scratch[768 + tid]) + b_r;
      float zv = (scratch[1024 + tid] + scratch[1280 + tid]) +
                 (scratch[1536 + tid] + scratch[1792 + tid]) + b_z;
      float rg = 1.f / (1.f + __expf(-rv));
      zt_reg = 1.f / (1.f + __expf(-zv));
      float hrv = hown * rg;
      unsigned short hb = f2bf(hrv);
      unsigned short lb = f2bf(hrv - bf2f(hb));
      st_coh_u32(hr2 + ((size_t)((t & 1) * 64 + 8 * g + bl)) * 512 + C1 + cl,
                 ((u32)hb << 16) | lb);
    }
    asm volatile("s_waitcnt vmcnt(0)" ::: "memory");
    if (wv < 2 && lane == 0) st_coh_u32(myflag, 2 * (u32)t + 1);

    // ================= phase 2: xu pre-GEMM + x(t+1) split (pre-poll), then hr
    f32x4 au = {0.f, 0.f, 0.f, 0.f};
#pragma unroll
    for (int j = 0; j < 2; ++j) {
      bf16x8 bu = *(const bf16x8*)&wlo[((48 + wv + 4 * j) * 64 + lane) * 8];
      chunk3(xhi[j], xlo[j], wuhi[j], bu, au);
    }
    if (t + 1 < TT) split_x(t + 1);
    poll(2 * (u32)t + 1);
    {
      const u64* hrb = (const u64*)(hr2 + ((size_t)((t & 1) * 64 + 8 * g + arow)) * 512 +
                                    32 * wv + kgrp * 8);
      u64 Q[16];
#pragma unroll
      for (int p = 0; p < 4; ++p) {
        Q[4 * p + 0] = ld_coh_u64(hrb + 64 * p + 0);
        Q[4 * p + 1] = ld_coh_u64(hrb + 64 * p + 1);
        Q[4 * p + 2] = ld_coh_u64(hrb + 64 * p + 2);
        Q[4 * p + 3] = ld_coh_u64(hrb + 64 * p + 3);
      }
#pragma unroll
      for (int p = 0; p < 4; ++p) {
        bf16x8 ahi, alo;
#pragma unroll
        for (int i = 0; i < 4; ++i) {
          u32 lo32 = (u32)Q[4 * p + i], hi32 = (u32)(Q[4 * p + i] >> 32);
          ahi[2 * i] = (short)(lo32 >> 16);
          alo[2 * i] = (short)lo32;
          ahi[2 * i + 1] = (short)(hi32 >> 16);
          alo[2 * i + 1] = (short)hi32;
        }
        const int j = p + 2;
        bf16x8 bu = *(const bf16x8*)&wlo[((48 + wv + 4 * j) * 64 + lane) * 8];
        chunk3(ahi, alo, wuhi[j], bu, au);
      }
    }
    __syncthreads();  // WAR: phase-1 reduce reads done
#pragma unroll
    for (int r = 0; r < 4; ++r)
      scratch[wv * 256 + (kgrp * 4 + r) * 16 + c] = au[r];
    __syncthreads();
    if (tid < 128) {
      float uv = (scratch[tid] + scratch[256 + tid]) +
                 (scratch[512 + tid] + scratch[768 + tid]) + b_u;
      float e = __expf(2.f * uv);
      float th = 1.f - 2.f / (e + 1.f);  // tanh(uv)
      float hn = hown + zt_reg * (th - hown);
      hown = hn;
      unsigned short hb = f2bf(hn);
      unsigned short lb = f2bf(hn - bf2f(hb));
      st_coh_u32(h2 + ((size_t)((t & 1) * 64 + 8 * g + bl)) * 512 + C1 + cl,
                 ((u32)hb << 16) | lb);
      if (t == TT - 1) out[(size_t)(8 * g + bl) * UU + C1 + cl] = hn;
    }
    asm volatile("s_waitcnt vmcnt(0)" ::: "memory");
    if (wv < 2 && lane == 0) st_coh_u32(myflag, 2 * (u32)t + 2);

    // ---- next-step phase-1 x-partials (pre-poll work)
    ar = (f32x4){0.f, 0.f, 0.f, 0.f};
    az = (f32x4){0.f, 0.f, 0.f, 0.f};
    if (t + 1 < TT) {
#pragma unroll
      for (int j = 0; j < 2; ++j) {
        bf16x8 br = *(const bf16x8*)&wlo[((wv + 4 * j) * 64 + lane) * 8];
        bf16x8 bz = *(const bf16x8*)&wlo[((24 + wv + 4 * j) * 64 + lane) * 8];
        chunk3(xhi[j], xlo[j], wrhi[j], br, ar);
        chunk3(xhi[j], xlo[j], wzhi[j], bz, az);
      }
    }
  }
}

extern "C" void kernel_launch(void* const* d_in, const int* in_sizes, int n_in,
                              void* d_out, int out_size, void* d_ws,
                              size_t ws_size, hipStream_t stream) {
  (void)in_sizes; (void)n_in; (void)out_size; (void)ws_size;
  hipMemsetAsync(d_ws, 0, WS_BYTES, stream);  // h(-1)=0, flags=0 (ready @ t=0)
  gru_persist<<<dim3(256), dim3(256), 0, stream>>>(
      (const float*)d_in[0], (const float*)d_in[1], (const float*)d_in[2],
      (const float*)d_in[3], (const float*)d_in[4], (const float*)d_in[5],
      (const float*)d_in[6], (float*)d_out, (unsigned char*)d_ws);
}